// Round 2
// baseline (6997.330 us; speedup 1.0000x reference)
//
#include <hip/hip_runtime.h>
#include <hip/hip_fp16.h>

#define NA 100000
#define NBATCH 4096

union H8 { uint4 u; __half h[8]; };

// ---------------- CSR build ----------------

struct MapsParams {
  const int* row[6];
  int cnt_off[6];
  int start[6];
  int total;
};

__global__ __launch_bounds__(256) void k_count(MapsParams mp, int* cnt) {
  for (int g = blockIdx.x * 256 + threadIdx.x; g < mp.total; g += gridDim.x * 256) {
    int m = 0;
#pragma unroll
    for (int i = 1; i < 6; i++) if (g >= mp.start[i]) m = i;
    int e = g - mp.start[m];
    atomicAdd(&cnt[mp.cnt_off[m] + mp.row[m][e]], 1);
  }
}

__global__ __launch_bounds__(256) void k_fill(MapsParams mp, int* cursor, int* bucket) {
  for (int g = blockIdx.x * 256 + threadIdx.x; g < mp.total; g += gridDim.x * 256) {
    int m = 0;
#pragma unroll
    for (int i = 1; i < 6; i++) if (g >= mp.start[i]) m = i;
    int e = g - mp.start[m];
    int pos = atomicAdd(&cursor[mp.cnt_off[m] + mp.row[m][e]], 1);
    bucket[pos] = e;
  }
}

__global__ __launch_bounds__(256) void k_scanA(const int* in, int* out, int* bsums, int n) {
  __shared__ int s[256];
  int t = threadIdx.x;
  int base = blockIdx.x * 2048 + t * 8;
  int v[8]; int sum = 0;
#pragma unroll
  for (int i = 0; i < 8; i++) { v[i] = (base + i < n) ? in[base + i] : 0; sum += v[i]; }
  s[t] = sum;
  __syncthreads();
  for (int d = 1; d < 256; d <<= 1) {
    int x = (t >= d) ? s[t - d] : 0;
    __syncthreads();
    s[t] += x;
    __syncthreads();
  }
  if (t == 255) bsums[blockIdx.x] = s[255];
  int run = s[t] - sum;
#pragma unroll
  for (int i = 0; i < 8; i++) { if (base + i < n) out[base + i] = run; run += v[i]; }
}

__global__ __launch_bounds__(256) void k_scanB(int* a, int n) {
  __shared__ int s[256];
  int t = threadIdx.x;
  int carry = 0;
  for (int c0 = 0; c0 < n; c0 += 256) {
    int v = (c0 + t < n) ? a[c0 + t] : 0;
    s[t] = v;
    __syncthreads();
    for (int d = 1; d < 256; d <<= 1) {
      int x = (t >= d) ? s[t - d] : 0;
      __syncthreads();
      s[t] += x;
      __syncthreads();
    }
    if (c0 + t < n) a[c0 + t] = s[t] - v + carry;
    int tot = s[255];
    __syncthreads();
    carry += tot;
  }
}

__global__ __launch_bounds__(256) void k_scanC(int* out, const int* bsums, int n) {
  int addv = bsums[blockIdx.x];
  int base = blockIdx.x * 2048 + threadIdx.x * 8;
#pragma unroll
  for (int i = 0; i < 8; i++) if (base + i < n) out[base + i] += addv;
}

// ---------------- feature init ----------------

__global__ __launch_bounds__(256) void k_atom_init(const int* xa, const float* e0,
                                                   const float* e1, const float* e2, float* x) {
  int idx = blockIdx.x * 256 + threadIdx.x;  // float4 index
  if (idx >= NA * 16) return;
  int a = idx >> 4, q = idx & 15;
  int f0 = xa[a * 3], f1 = xa[a * 3 + 1], f2 = xa[a * 3 + 2];
  float4 v0 = ((const float4*)e0)[f0 * 16 + q];
  float4 v1 = ((const float4*)e1)[f1 * 16 + q];
  float4 v2 = ((const float4*)e2)[f2 * 16 + q];
  float4 o;
  o.x = v0.x + v1.x + v2.x; o.y = v0.y + v1.y + v2.y;
  o.z = v0.z + v1.z + v2.z; o.w = v0.w + v1.w + v2.w;
  ((float4*)x)[idx] = o;
}

struct PInit {
  __half* dst[5];
  const int* vals[5];
  const float* tab[5];
  int start8[5];  // cumulative half8-chunk starts
  int total8;
};

__global__ __launch_bounds__(256) void k_path_init(PInit pp) {
  for (int g = blockIdx.x * 256 + threadIdx.x; g < pp.total8; g += gridDim.x * 256) {
    int m = 0;
#pragma unroll
    for (int i = 1; i < 5; i++) if (g >= pp.start8[i]) m = i;
    int lc = g - pp.start8[m];
    int e = lc >> 3, q = lc & 7;
    int v = pp.vals[m][e];
    const float* src = pp.tab[m] + v * 64 + q * 8;
    H8 o;
#pragma unroll
    for (int j = 0; j < 8; j++) o.h[j] = __float2half(src[j]);
    ((uint4*)pp.dst[m])[lc] = o.u;
  }
}

// ---------------- a2p: xp = xp + relu(gather(x) @ W + b), fp16 out ----------------

struct A2pParams {
  const float* x;
  const int* gidx[3];
  __half* out[3];
  const float* W[3];
  const float* bias[3];
  int blk_start[3];
  int nseg;
};

__global__ __launch_bounds__(256) void k_a2p(A2pParams p) {
  __shared__ float Wl[4096];
  __shared__ float inl[32 * 64];
  __shared__ float bl[64];
  __shared__ int ridx[32];
  int bid = blockIdx.x;
  int seg = 0;
#pragma unroll
  for (int i = 1; i < 3; i++) if (i < p.nseg && bid >= p.blk_start[i]) seg = i;
  int brow = (bid - p.blk_start[seg]) * 32;  // all E divisible by 32: no tail
  int t = threadIdx.x;
#pragma unroll
  for (int i = 0; i < 4; i++)
    ((float4*)Wl)[t + 256 * i] = ((const float4*)p.W[seg])[t + 256 * i];
  if (t < 64) bl[t] = p.bias[seg][t];
  if (t < 32) ridx[t] = p.gidx[seg][brow + t];
  __syncthreads();
#pragma unroll
  for (int i = 0; i < 2; i++) {
    int idx = t + 256 * i;
    int r = idx >> 4, q = idx & 15;
    ((float4*)inl)[idx] = ((const float4*)(p.x + (long)ridx[r] * 64))[q];
  }
  __syncthreads();
  int c = t & 63, rq = t >> 6;
  float acc[8];
#pragma unroll
  for (int i = 0; i < 8; i++) acc[i] = 0.f;
  for (int j = 0; j < 64; j += 4) {
    float w0 = Wl[(j + 0) * 64 + c], w1 = Wl[(j + 1) * 64 + c];
    float w2 = Wl[(j + 2) * 64 + c], w3 = Wl[(j + 3) * 64 + c];
#pragma unroll
    for (int i = 0; i < 8; i++) {
      int r = rq * 8 + i;
      float4 v = *(const float4*)&inl[r * 64 + j];
      acc[i] += v.x * w0 + v.y * w1 + v.z * w2 + v.w * w3;
    }
  }
  float bv = bl[c];
  __half* out = p.out[seg];
#pragma unroll
  for (int i = 0; i < 8; i++) {
    long e = brow + rq * 8 + i;
    float v = acc[i] + bv;
    v = v > 0.f ? v : 0.f;
    float r32 = __half2float(out[e * 64 + c]);
    out[e * 64 + c] = __float2half(r32 + v);
  }
}

// ---------------- in-place width-3 path conv on fp16 buf ----------------

struct ConvParams {
  __half* buf[3];
  const float* Kp[3];   // [3][64][64]
  const float* Kb[3];
  int k[3];
  int P[3];
  int ppb[3];
  int blk_start[3];
  int nseg;
  int cyclic;
};

__global__ __launch_bounds__(256) void k_conv(ConvParams p) {
  __shared__ float Kl[3 * 64 * 64];  // 48KB
  __shared__ float rl[48 * 64];      // 12KB
  __shared__ float kbl[64];
  int bid = blockIdx.x;
  int seg = 0;
#pragma unroll
  for (int i = 1; i < 3; i++) if (i < p.nseg && bid >= p.blk_start[i]) seg = i;
  int kk = p.k[seg], ppb = p.ppb[seg], P = p.P[seg];
  __half* buf = p.buf[seg];
  int t = threadIdx.x;
  {
    const float4* Ks = (const float4*)p.Kp[seg];
    float4* Kd = (float4*)Kl;
    if (p.cyclic) {
#pragma unroll
      for (int i = 0; i < 12; i++) {
        int idx = t + 256 * i;
        int w = idx >> 10, r = idx & 1023;
        float4 a = Ks[idx];
        float4 b = Ks[(2 - w) * 1024 + r];
        float4 o;
        o.x = 0.5f * (a.x + b.x); o.y = 0.5f * (a.y + b.y);
        o.z = 0.5f * (a.z + b.z); o.w = 0.5f * (a.w + b.w);
        Kd[idx] = o;
      }
    } else {
#pragma unroll
      for (int i = 0; i < 12; i++) Kd[t + 256 * i] = Ks[t + 256 * i];
    }
  }
  if (t < 64) kbl[t] = p.Kb[seg][t];
  int p0 = (bid - p.blk_start[seg]) * ppb;
  int npaths = min(ppb, P - p0);
  int R = npaths * kk;
  long ebase = (long)p0 * kk;
  {
    const uint4* src = (const uint4*)(buf + ebase * 64);
    for (int idx = t; idx < R * 8; idx += 256) {
      H8 v; v.u = src[idx];
      float* d = &rl[idx * 8];
#pragma unroll
      for (int j = 0; j < 8; j++) d[j] = __half2float(v.h[j]);
    }
  }
  __syncthreads();
  int c = t & 63, rq = t >> 6;
  float acc[12];
#pragma unroll
  for (int i = 0; i < 12; i++) acc[i] = kbl[c];
  int pp_[12], ss_[12];
#pragma unroll
  for (int i = 0; i < 12; i++) {
    int r = rq + 4 * i;
    int pq = r / kk;
    pp_[i] = pq;
    ss_[i] = r - pq * kk;
  }
  for (int w = 0; w < 3; w++) {
    int src_[12];
#pragma unroll
    for (int i = 0; i < 12; i++) {
      int r = rq + 4 * i;
      int sr = ss_[i] + w - 1;
      if (p.cyclic) sr = (sr < 0) ? (kk - 1) : ((sr >= kk) ? 0 : sr);
      src_[i] = (r < R && sr >= 0 && sr < kk) ? (pp_[i] * kk + sr) : -1;
    }
    const float* Kw = &Kl[w * 4096];
    for (int j = 0; j < 64; j += 4) {
      float w0 = Kw[(j + 0) * 64 + c], w1 = Kw[(j + 1) * 64 + c];
      float w2 = Kw[(j + 2) * 64 + c], w3 = Kw[(j + 3) * 64 + c];
#pragma unroll
      for (int i = 0; i < 12; i++) {
        if (src_[i] >= 0) {
          float4 v = *(const float4*)&rl[src_[i] * 64 + j];
          acc[i] += v.x * w0 + v.y * w1 + v.z * w2 + v.w * w3;
        }
      }
    }
  }
#pragma unroll
  for (int i = 0; i < 12; i++) {
    int r = rq + 4 * i;
    if (r < R) {
      float v = acc[i];
      v = v > 0.f ? v : 0.f;
      buf[(ebase + r) * 64 + c] = __float2half(rl[r * 64 + c] + v);
    }
  }
}

// ---------------- fused p2a: x += sum_m relu(csr_mean(xp_m) @ W_m + b_m) ----------------

struct P2aParams {
  float* x;
  const __half* xp[3];
  const int* bucket;
  const int* basea;
  const int* cnt;
  int off[3];
  const float* W[3];
  const float* bias[3];
  int nmaps;
};

__global__ __launch_bounds__(256) void k_p2a(P2aParams p) {
  __shared__ float Wl[3 * 4096];  // 48KB
  __shared__ float inl[32 * 64];
  __shared__ float bl[3 * 64];
  __shared__ int sb0[32], sbc[32];
  int t = threadIdx.x;
  int brow = blockIdx.x * 32;  // NA divisible by 32
  int nm = p.nmaps;
  for (int m = 0; m < nm; m++) {
#pragma unroll
    for (int i = 0; i < 4; i++)
      ((float4*)(Wl + m * 4096))[t + 256 * i] = ((const float4*)p.W[m])[t + 256 * i];
    if (t < 64) bl[m * 64 + t] = p.bias[m][t];
  }
  int c = t & 63, rq = t >> 6;
  float addv[8];
#pragma unroll
  for (int i = 0; i < 8; i++) addv[i] = 0.f;
  for (int m = 0; m < nm; m++) {
    __syncthreads();  // W/b ready (m=0); inl/sb free of prior readers (m>0)
    if (t < 32) {
      sb0[t] = p.basea[p.off[m] + brow + t];
      sbc[t] = p.cnt[p.off[m] + brow + t];
    }
    __syncthreads();
    const __half* src = p.xp[m];
#pragma unroll
    for (int i = 0; i < 8; i++) {
      int r = rq * 8 + i;
      int b0 = sb0[r], bc = sbc[r];
      float s = 0.f;
      for (int j = 0; j < bc; j++) {
        int e = p.bucket[b0 + j];
        s += __half2float(src[(long)e * 64 + c]);
      }
      inl[r * 64 + c] = s / (float)(bc > 0 ? bc : 1);
    }
    __syncthreads();
    float acc[8];
#pragma unroll
    for (int i = 0; i < 8; i++) acc[i] = 0.f;
    const float* Wm = Wl + m * 4096;
    for (int j = 0; j < 64; j += 4) {
      float w0 = Wm[(j + 0) * 64 + c], w1 = Wm[(j + 1) * 64 + c];
      float w2 = Wm[(j + 2) * 64 + c], w3 = Wm[(j + 3) * 64 + c];
#pragma unroll
      for (int i = 0; i < 8; i++) {
        int r = rq * 8 + i;
        float4 v = *(const float4*)&inl[r * 64 + j];
        acc[i] += v.x * w0 + v.y * w1 + v.z * w2 + v.w * w3;
      }
    }
    float bv = bl[m * 64 + c];
#pragma unroll
    for (int i = 0; i < 8; i++) {
      float v = acc[i] + bv;
      addv[i] += v > 0.f ? v : 0.f;
    }
  }
#pragma unroll
  for (int i = 0; i < 8; i++) {
    long a = brow + rq * 8 + i;
    p.x[a * 64 + c] += addv[i];
  }
}

// ---------------- batch mean: g1[b] = mean(x[a]) over CSR bucket ----------------

__global__ __launch_bounds__(256) void k_meanscatter(const float* src, const int* bucket,
                                                     const int* basea, const int* cnta,
                                                     float* dst, int nseg) {
  int wid = (blockIdx.x * 256 + threadIdx.x) >> 6;
  int lane = threadIdx.x & 63;
  if (wid >= nseg) return;
  int b0 = basea[wid], cnt = cnta[wid];
  float s = 0.f;
  for (int i = 0; i < cnt; i++) {
    int e = bucket[b0 + i];
    s += src[(long)e * 64 + lane];
  }
  dst[(long)wid * 64 + lane] = s / (float)(cnt > 0 ? cnt : 1);
}

// ---------------- head gemm: g2 = relu(g1 @ W + b) ----------------

__global__ __launch_bounds__(256) void k_head(const float* g1, const float* W,
                                              const float* bias, float* g2) {
  __shared__ float Wl[4096];
  __shared__ float inl[32 * 64];
  __shared__ float bl[64];
  int t = threadIdx.x;
  int brow = blockIdx.x * 32;
#pragma unroll
  for (int i = 0; i < 4; i++) ((float4*)Wl)[t + 256 * i] = ((const float4*)W)[t + 256 * i];
  if (t < 64) bl[t] = bias[t];
  __syncthreads();
#pragma unroll
  for (int i = 0; i < 2; i++) {
    int idx = t + 256 * i;
    int r = idx >> 4, q = idx & 15;
    ((float4*)inl)[idx] = ((const float4*)(g1 + (long)(brow + r) * 64))[q];
  }
  __syncthreads();
  int c = t & 63, rq = t >> 6;
  float acc[8];
#pragma unroll
  for (int i = 0; i < 8; i++) acc[i] = 0.f;
  for (int j = 0; j < 64; j += 4) {
    float w0 = Wl[(j + 0) * 64 + c], w1 = Wl[(j + 1) * 64 + c];
    float w2 = Wl[(j + 2) * 64 + c], w3 = Wl[(j + 3) * 64 + c];
#pragma unroll
    for (int i = 0; i < 8; i++) {
      int r = rq * 8 + i;
      float4 v = *(const float4*)&inl[r * 64 + j];
      acc[i] += v.x * w0 + v.y * w1 + v.z * w2 + v.w * w3;
    }
  }
#pragma unroll
  for (int i = 0; i < 8; i++) {
    long r = brow + rq * 8 + i;
    float v = acc[i] + bl[c];
    g2[r * 64 + c] = v > 0.f ? v : 0.f;
  }
}

__global__ __launch_bounds__(256) void k_final(const float* g2, const float* linW,
                                               const float* linb, float* out) {
  int wid = (blockIdx.x * 256 + threadIdx.x) >> 6;
  int lane = threadIdx.x & 63;
  if (wid >= NBATCH) return;
  float v = g2[(long)wid * 64 + lane] * linW[lane];
  for (int o = 32; o > 0; o >>= 1) v += __shfl_down(v, o, 64);
  if (lane == 0) out[wid] = v + linb[0];
}

__global__ __launch_bounds__(256) void k_zero_out(float* out, int n) {
  for (int i = blockIdx.x * 256 + threadIdx.x; i < n; i += gridDim.x * 256) out[i] = 0.f;
}

// ---------------- launcher ----------------

extern "C" void kernel_launch(void* const* d_in, const int* in_sizes, int n_in,
                              void* d_out, int out_size, void* d_ws, size_t ws_size,
                              hipStream_t stream) {
  (void)in_sizes; (void)n_in;

  const int* x_atom = (const int*)d_in[0];
  const int* vals[5] = {(const int*)d_in[1], (const int*)d_in[4], (const int*)d_in[7],
                        (const int*)d_in[10], (const int*)d_in[13]};
  const int* rowm[5] = {(const int*)d_in[2], (const int*)d_in[5], (const int*)d_in[8],
                        (const int*)d_in[11], (const int*)d_in[14]};
  const int* batch = (const int*)d_in[16];
  const float* aemb0 = (const float*)d_in[17];
  const float* aemb1 = (const float*)d_in[18];
  const float* aemb2 = (const float*)d_in[19];
  const float* path_emb = (const float*)d_in[20];
  const float* cycle_emb = (const float*)d_in[21];
  const float* pW_a2p = (const float*)d_in[22];
  const float* pb_a2p = (const float*)d_in[23];
  const float* pW_p2a = (const float*)d_in[24];
  const float* pb_p2a = (const float*)d_in[25];
  const float* pK = (const float*)d_in[26];
  const float* pKb = (const float*)d_in[27];
  const float* cW_a2p = (const float*)d_in[28];
  const float* cb_a2p = (const float*)d_in[29];
  const float* cW_p2a = (const float*)d_in[30];
  const float* cb_p2a = (const float*)d_in[31];
  const float* cK = (const float*)d_in[32];
  const float* cKb = (const float*)d_in[33];
  const float* alW = (const float*)d_in[34];
  const float* alb = (const float*)d_in[35];
  const float* linW = (const float*)d_in[36];
  const float* linb = (const float*)d_in[37];

  static const int Em[5] = {300000, 400000, 500000, 200000, 240000};
  static const int Km[5] = {3, 4, 5, 5, 6};
  const int CNT_N = 5 * 100000 + NBATCH;  // 504096
  const int BUCKET_N = 1640000 + 100000;  // 1740000

  char* ws = (char*)d_ws;
  size_t off = 0;
  auto alloc = [&](size_t nbytes) -> char* {
    char* p = ws + off;
    off = (off + nbytes + 255) & ~(size_t)255;
    return p;
  };
  float* x = (float*)alloc((size_t)NA * 64 * 4);
  __half* xp[5];
  for (int m = 0; m < 5; m++) xp[m] = (__half*)alloc((size_t)Em[m] * 64 * 2);
  float* g1 = (float*)alloc((size_t)NBATCH * 64 * 4);
  float* g2 = (float*)alloc((size_t)NBATCH * 64 * 4);
  int* cnt = (int*)alloc((size_t)CNT_N * 4);
  int* basea = (int*)alloc((size_t)CNT_N * 4);
  int* cursor = (int*)alloc((size_t)CNT_N * 4);
  int* bucket = (int*)alloc((size_t)BUCKET_N * 4);
  int* bsums = (int*)alloc(256 * 4);

  if (ws_size < off) {  // workspace too small: emit readable failure, not a fault
    k_zero_out<<<16, 256, 0, stream>>>((float*)d_out, out_size);
    return;
  }

  // ---- CSR build
  MapsParams mp;
  {
    int s = 0;
    for (int m = 0; m < 5; m++) {
      mp.row[m] = rowm[m]; mp.cnt_off[m] = m * 100000;
      mp.start[m] = s; s += Em[m];
    }
    mp.row[5] = batch; mp.cnt_off[5] = 500000; mp.start[5] = s;
    mp.total = s + NA;
  }
  hipMemsetAsync(cnt, 0, (size_t)CNT_N * 4, stream);
  k_count<<<2048, 256, 0, stream>>>(mp, cnt);
  int nbScan = (CNT_N + 2047) / 2048;  // 247
  k_scanA<<<nbScan, 256, 0, stream>>>(cnt, basea, bsums, CNT_N);
  k_scanB<<<1, 256, 0, stream>>>(bsums, nbScan);
  k_scanC<<<nbScan, 256, 0, stream>>>(basea, bsums, CNT_N);
  hipMemcpyAsync(cursor, basea, (size_t)CNT_N * 4, hipMemcpyDeviceToDevice, stream);
  k_fill<<<2048, 256, 0, stream>>>(mp, cursor, bucket);

  // ---- feature init
  k_atom_init<<<NA * 16 / 256, 256, 0, stream>>>(x_atom, aemb0, aemb1, aemb2, x);
  {
    PInit pp;
    int s8 = 0;
    for (int m = 0; m < 5; m++) {
      pp.dst[m] = xp[m];
      pp.vals[m] = vals[m];
      pp.tab[m] = (m < 3) ? (path_emb + m * 6 * 64) : (cycle_emb + (m - 3) * 4 * 64);
      pp.start8[m] = s8;
      s8 += Em[m] * 8;
    }
    pp.total8 = s8;
    k_path_init<<<8192, 256, 0, stream>>>(pp);
  }

  // ---- layers
  for (int l = 0; l < 2; l++) {
    // === paths group (maps 0..2), non-cyclic
    {
      A2pParams gp{};
      gp.nseg = 3; gp.x = x;
      int bs = 0;
      for (int m = 0; m < 3; m++) {
        gp.gidx[m] = rowm[m]; gp.out[m] = xp[m];
        gp.W[m] = pW_a2p + (l * 3 + m) * 4096;
        gp.bias[m] = pb_a2p + (l * 3 + m) * 64;
        gp.blk_start[m] = bs;
        bs += Em[m] / 32;
      }
      k_a2p<<<bs, 256, 0, stream>>>(gp);

      ConvParams cp{};
      cp.nseg = 3; cp.cyclic = 0;
      int cbs = 0;
      for (int m = 0; m < 3; m++) {
        cp.buf[m] = xp[m];
        cp.Kp[m] = pK + (size_t)((l * 3 + m) * 3) * 4096;
        cp.Kb[m] = pKb + (l * 3 + m) * 64;
        cp.k[m] = Km[m]; cp.P[m] = Em[m] / Km[m]; cp.ppb[m] = 48 / Km[m];
        cp.blk_start[m] = cbs;
        cbs += (cp.P[m] + cp.ppb[m] - 1) / cp.ppb[m];
      }
      k_conv<<<cbs, 256, 0, stream>>>(cp);

      P2aParams bp{};
      bp.x = x; bp.bucket = bucket; bp.basea = basea; bp.cnt = cnt; bp.nmaps = 3;
      for (int m = 0; m < 3; m++) {
        bp.xp[m] = xp[m]; bp.off[m] = m * 100000;
        bp.W[m] = pW_p2a + (l * 3 + m) * 4096;
        bp.bias[m] = pb_p2a + (l * 3 + m) * 64;
      }
      k_p2a<<<NA / 32, 256, 0, stream>>>(bp);
    }
    // === cycles group (maps 3..4), cyclic
    {
      A2pParams gp{};
      gp.nseg = 2; gp.x = x;
      int bs = 0;
      for (int m = 3; m < 5; m++) {
        int i = m - 3;
        gp.gidx[i] = rowm[m]; gp.out[i] = xp[m];
        gp.W[i] = cW_a2p + (l * 2 + i) * 4096;
        gp.bias[i] = cb_a2p + (l * 2 + i) * 64;
        gp.blk_start[i] = bs;
        bs += Em[m] / 32;
      }
      k_a2p<<<bs, 256, 0, stream>>>(gp);

      ConvParams cp{};
      cp.nseg = 2; cp.cyclic = 1;
      int cbs = 0;
      for (int m = 3; m < 5; m++) {
        int i = m - 3;
        cp.buf[i] = xp[m];
        cp.Kp[i] = cK + (size_t)((l * 2 + i) * 3) * 4096;
        cp.Kb[i] = cKb + (l * 2 + i) * 64;
        cp.k[i] = Km[m]; cp.P[i] = Em[m] / Km[m]; cp.ppb[i] = 48 / Km[m];
        cp.blk_start[i] = cbs;
        cbs += (cp.P[i] + cp.ppb[i] - 1) / cp.ppb[i];
      }
      k_conv<<<cbs, 256, 0, stream>>>(cp);

      P2aParams bp{};
      bp.x = x; bp.bucket = bucket; bp.basea = basea; bp.cnt = cnt; bp.nmaps = 2;
      for (int m = 3; m < 5; m++) {
        int i = m - 3;
        bp.xp[i] = xp[m]; bp.off[i] = m * 100000;
        bp.W[i] = cW_p2a + (l * 2 + i) * 4096;
        bp.bias[i] = cb_p2a + (l * 2 + i) * 64;
      }
      k_p2a<<<NA / 32, 256, 0, stream>>>(bp);
    }
  }

  // ---- head
  k_meanscatter<<<NBATCH / 4, 256, 0, stream>>>(x, bucket, basea + 500000, cnt + 500000,
                                                g1, NBATCH);
  k_head<<<NBATCH / 32, 256, 0, stream>>>(g1, alW, alb, g2);
  k_final<<<NBATCH / 4, 256, 0, stream>>>(g2, linW, linb, (float*)d_out);
}

// Round 3
// 3023.494 us; speedup vs baseline: 2.3143x; 2.3143x over previous
//
#include <hip/hip_runtime.h>
#include <hip/hip_fp16.h>

#define NA 100000
#define NBATCH 4096

typedef _Float16 f16;
typedef f16 half8 __attribute__((ext_vector_type(8)));
typedef float f32x4 __attribute__((ext_vector_type(4)));
union H8 { uint4 u; __half h[8]; };
union HU { uint4 u; half8 h; };

// ---------------- CSR build ----------------

struct MapsParams {
  const int* row[6];
  int cnt_off[6];
  int start[6];
  int total;
};

__global__ __launch_bounds__(256) void k_count(MapsParams mp, int* cnt) {
  for (int g = blockIdx.x * 256 + threadIdx.x; g < mp.total; g += gridDim.x * 256) {
    int m = 0;
#pragma unroll
    for (int i = 1; i < 6; i++) if (g >= mp.start[i]) m = i;
    int e = g - mp.start[m];
    atomicAdd(&cnt[mp.cnt_off[m] + mp.row[m][e]], 1);
  }
}

__global__ __launch_bounds__(256) void k_fill(MapsParams mp, int* cursor, int* bucket) {
  for (int g = blockIdx.x * 256 + threadIdx.x; g < mp.total; g += gridDim.x * 256) {
    int m = 0;
#pragma unroll
    for (int i = 1; i < 6; i++) if (g >= mp.start[i]) m = i;
    int e = g - mp.start[m];
    int pos = atomicAdd(&cursor[mp.cnt_off[m] + mp.row[m][e]], 1);
    bucket[pos] = e;
  }
}

__global__ __launch_bounds__(256) void k_scanA(const int* in, int* out, int* bsums, int n) {
  __shared__ int s[256];
  int t = threadIdx.x;
  int base = blockIdx.x * 2048 + t * 8;
  int v[8]; int sum = 0;
#pragma unroll
  for (int i = 0; i < 8; i++) { v[i] = (base + i < n) ? in[base + i] : 0; sum += v[i]; }
  s[t] = sum;
  __syncthreads();
  for (int d = 1; d < 256; d <<= 1) {
    int x = (t >= d) ? s[t - d] : 0;
    __syncthreads();
    s[t] += x;
    __syncthreads();
  }
  if (t == 255) bsums[blockIdx.x] = s[255];
  int run = s[t] - sum;
#pragma unroll
  for (int i = 0; i < 8; i++) { if (base + i < n) out[base + i] = run; run += v[i]; }
}

__global__ __launch_bounds__(256) void k_scanB(int* a, int n) {
  __shared__ int s[256];
  int t = threadIdx.x;
  int carry = 0;
  for (int c0 = 0; c0 < n; c0 += 256) {
    int v = (c0 + t < n) ? a[c0 + t] : 0;
    s[t] = v;
    __syncthreads();
    for (int d = 1; d < 256; d <<= 1) {
      int x = (t >= d) ? s[t - d] : 0;
      __syncthreads();
      s[t] += x;
      __syncthreads();
    }
    if (c0 + t < n) a[c0 + t] = s[t] - v + carry;
    int tot = s[255];
    __syncthreads();
    carry += tot;
  }
}

__global__ __launch_bounds__(256) void k_scanC(int* out, const int* bsums, int n) {
  int addv = bsums[blockIdx.x];
  int base = blockIdx.x * 2048 + threadIdx.x * 8;
#pragma unroll
  for (int i = 0; i < 8; i++) if (base + i < n) out[base + i] += addv;
}

// ---------------- feature init ----------------

__global__ __launch_bounds__(256) void k_atom_init(const int* xa, const float* e0,
                                                   const float* e1, const float* e2, float* x) {
  int idx = blockIdx.x * 256 + threadIdx.x;  // float4 index
  if (idx >= NA * 16) return;
  int a = idx >> 4, q = idx & 15;
  int f0 = xa[a * 3], f1 = xa[a * 3 + 1], f2 = xa[a * 3 + 2];
  float4 v0 = ((const float4*)e0)[f0 * 16 + q];
  float4 v1 = ((const float4*)e1)[f1 * 16 + q];
  float4 v2 = ((const float4*)e2)[f2 * 16 + q];
  float4 o;
  o.x = v0.x + v1.x + v2.x; o.y = v0.y + v1.y + v2.y;
  o.z = v0.z + v1.z + v2.z; o.w = v0.w + v1.w + v2.w;
  ((float4*)x)[idx] = o;
}

struct PInit {
  __half* dst[5];
  const int* vals[5];
  const float* tab[5];
  int start8[5];  // cumulative half8-chunk starts
  int total8;
};

__global__ __launch_bounds__(256) void k_path_init(PInit pp) {
  for (int g = blockIdx.x * 256 + threadIdx.x; g < pp.total8; g += gridDim.x * 256) {
    int m = 0;
#pragma unroll
    for (int i = 1; i < 5; i++) if (g >= pp.start8[i]) m = i;
    int lc = g - pp.start8[m];
    int e = lc >> 3, q = lc & 7;
    int v = pp.vals[m][e];
    const float* src = pp.tab[m] + v * 64 + q * 8;
    H8 o;
#pragma unroll
    for (int j = 0; j < 8; j++) o.h[j] = __float2half(src[j]);
    ((uint4*)pp.dst[m])[lc] = o.u;
  }
}

// ---------------- prepack conv kernels to fp16 MFMA-B layout ----------------
// layout per set: idx = ((nt*6+kc)*64 + lane)*8 + j ; B[k][n], k=kc*32+(lane>>4)*8+j, n=nt*16+(lane&15)
// sets 0..5: pK (l*3+m), non-cyclic. sets 6..9: cK (l*2+i), symmetrized.

__global__ __launch_bounds__(256) void k_prepB(const float* pK, const float* cK, f16* Bp) {
  int tid = blockIdx.x * 256 + threadIdx.x;
  if (tid >= 10 * 12288) return;
  int set = tid / 12288, pos = tid % 12288;
  int j = pos & 7, lane = (pos >> 3) & 63, kcnt = pos >> 9;
  int kc = kcnt % 6, nt = kcnt / 6;
  int k = kc * 32 + ((lane >> 4) << 3) + j;
  int n = (nt << 4) + (lane & 15);
  int w = k >> 6, ji = k & 63;
  const float* K = (set < 6) ? (pK + set * 3 * 4096) : (cK + (set - 6) * 3 * 4096);
  float v = K[w * 4096 + ji * 64 + n];
  if (set >= 6) v = 0.5f * (v + K[(2 - w) * 4096 + ji * 64 + n]);
  Bp[tid] = (f16)v;
}

// ---------------- a2p: xp = xp + relu(gather(x) @ W + b), fp16 out ----------------

struct A2pParams {
  const float* x;
  const int* gidx[3];
  __half* out[3];
  const float* W[3];
  const float* bias[3];
  int blk_start[3];
  int nseg;
};

__global__ __launch_bounds__(256) void k_a2p(A2pParams p) {
  __shared__ float Wl[4096];
  __shared__ float inl[32 * 64];
  __shared__ float bl[64];
  __shared__ int ridx[32];
  int bid = blockIdx.x;
  int seg = 0;
#pragma unroll
  for (int i = 1; i < 3; i++) if (i < p.nseg && bid >= p.blk_start[i]) seg = i;
  int brow = (bid - p.blk_start[seg]) * 32;  // all E divisible by 32: no tail
  int t = threadIdx.x;
#pragma unroll
  for (int i = 0; i < 4; i++)
    ((float4*)Wl)[t + 256 * i] = ((const float4*)p.W[seg])[t + 256 * i];
  if (t < 64) bl[t] = p.bias[seg][t];
  if (t < 32) ridx[t] = p.gidx[seg][brow + t];
  __syncthreads();
#pragma unroll
  for (int i = 0; i < 2; i++) {
    int idx = t + 256 * i;
    int r = idx >> 4, q = idx & 15;
    ((float4*)inl)[idx] = ((const float4*)(p.x + (long)ridx[r] * 64))[q];
  }
  __syncthreads();
  int c = t & 63, rq = t >> 6;
  float acc[8];
#pragma unroll
  for (int i = 0; i < 8; i++) acc[i] = 0.f;
  for (int j = 0; j < 64; j += 4) {
    float w0 = Wl[(j + 0) * 64 + c], w1 = Wl[(j + 1) * 64 + c];
    float w2 = Wl[(j + 2) * 64 + c], w3 = Wl[(j + 3) * 64 + c];
#pragma unroll
    for (int i = 0; i < 8; i++) {
      int r = rq * 8 + i;
      float4 v = *(const float4*)&inl[r * 64 + j];
      acc[i] += v.x * w0 + v.y * w1 + v.z * w2 + v.w * w3;
    }
  }
  float bv = bl[c];
  __half* out = p.out[seg];
#pragma unroll
  for (int i = 0; i < 8; i++) {
    long e = brow + rq * 8 + i;
    float v = acc[i] + bv;
    v = v > 0.f ? v : 0.f;
    float r32 = __half2float(out[e * 64 + c]);
    out[e * 64 + c] = __float2half(r32 + v);
  }
}

// ---------------- MFMA conv: buf = pre + relu([Rx192]@[192x64] + Kb) ----------------
// A-expanded packed in LDS in MFMA A-frag order; whole paths per block (in-place safe).

struct ConvParams {
  f16* buf[3];
  const f16* Bp[3];
  const float* Kb[3];
  int k[3];
  int P[3];
  int ppb[3];
  int blk_start[3];
  int nseg;
  int cyclic;
};

__global__ __launch_bounds__(256) void k_conv(ConvParams p) {
  __shared__ uint4 Apk[2304];  // up to 6 m-tiles * 6 kc * 64 lanes * 16B = 36864B
  __shared__ uint4 Bpk[1536];  // 4 nt * 6 kc * 64 * 16B = 24576B
  __shared__ float kbl[64];
  int bid = blockIdx.x;
  int seg = 0;
#pragma unroll
  for (int i = 1; i < 3; i++) if (i < p.nseg && bid >= p.blk_start[i]) seg = i;
  int kk = p.k[seg], ppb = p.ppb[seg], P = p.P[seg];
  f16* buf = p.buf[seg];
  int t = threadIdx.x;
  int p0 = (bid - p.blk_start[seg]) * ppb;
  int np = min(ppb, P - p0);
  int R = np * kk;       // always a multiple of 16 for our ppb choices
  int mtb = R >> 4;      // m-tiles: 4..6
  long ebase = (long)p0 * kk;
  {
    const uint4* bs = (const uint4*)p.Bp[seg];
    for (int i = t; i < 1536; i += 256) Bpk[i] = bs[i];
  }
  if (t < 64) kbl[t] = p.Kb[seg][t];
  {
    uint4 z; z.x = z.y = z.z = z.w = 0;
    int nU = mtb * 384;
    for (int i = t; i < nU; i += 256) Apk[i] = z;
  }
  __syncthreads();
  // fill A-expanded: source row r contributes its 8-half chunks to w=0,1,2 shifted rows
  {
    const uint4* src = (const uint4*)(buf + ebase * 64);
    int tot = R * 8;
    for (int idx = t; idx < tot; idx += 256) {
      int r = idx >> 3, jj = idx & 7;
      uint4 ch = src[idx];
      int s = r % kk;
      int kchi = jj >> 2, quad = jj & 3;
#pragma unroll
      for (int w = 0; w < 3; w++) {
        int rd;
        if (w == 1) rd = r;
        else if (w == 0) rd = (s + 1 < kk) ? r + 1 : (p.cyclic ? r + 1 - kk : -1);
        else rd = (s >= 1) ? r - 1 : (p.cyclic ? r + kk - 1 : -1);
        if (rd >= 0)
          Apk[((rd >> 4) * 6 + 2 * w + kchi) * 64 + quad * 16 + (rd & 15)] = ch;
      }
    }
  }
  __syncthreads();
  int lane = t & 63, wid = t >> 6;
  int wave_n = wid & 1, wave_m = wid >> 1;
  int mtA = (mtb + 1) >> 1;
  int m0 = wave_m ? mtA : 0;
  int mcnt = wave_m ? (mtb - mtA) : mtA;  // <= 3
  f32x4 acc[3][2];
#pragma unroll
  for (int i = 0; i < 3; i++)
#pragma unroll
    for (int jn = 0; jn < 2; jn++) {
      f32x4 z = {0.f, 0.f, 0.f, 0.f};
      acc[i][jn] = z;
    }
  for (int kc = 0; kc < 6; kc++) {
    HU a[3], b[2];
#pragma unroll
    for (int jn = 0; jn < 2; jn++)
      b[jn].u = Bpk[((wave_n * 2 + jn) * 6 + kc) * 64 + lane];
#pragma unroll
    for (int i = 0; i < 3; i++)
      if (i < mcnt) a[i].u = Apk[((m0 + i) * 6 + kc) * 64 + lane];
#pragma unroll
    for (int i = 0; i < 3; i++)
      if (i < mcnt) {
#pragma unroll
        for (int jn = 0; jn < 2; jn++)
          acc[i][jn] = __builtin_amdgcn_mfma_f32_16x16x32_f16(a[i].h, b[jn].h, acc[i][jn], 0, 0, 0);
      }
  }
  // epilogue: residual from the w=1 (identity) slice of packed A
  const f16* Ah = (const f16*)Apk;
#pragma unroll
  for (int i = 0; i < 3; i++) {
    if (i >= mcnt) continue;
    int mt = m0 + i;
#pragma unroll
    for (int jn = 0; jn < 2; jn++) {
      int n = (wave_n * 2 + jn) * 16 + (lane & 15);
      int kcr = 2 + (n >> 5), quadb = (n & 31) >> 3, jr = n & 7;
#pragma unroll
      for (int reg = 0; reg < 4; reg++) {
        int r = mt * 16 + ((lane >> 4) << 2) + reg;
        float pre = (float)Ah[(((mt * 6 + kcr) * 64 + quadb * 16 + (r & 15)) << 3) + jr];
        float v = acc[i][jn][reg] + kbl[n];
        v = v > 0.f ? v : 0.f;
        buf[(ebase + r) * 64 + n] = (f16)(pre + v);
      }
    }
  }
}

// ---------------- fused p2a: x += sum_m relu(csr_mean(xp_m) @ W_m + b_m) ----------------

struct P2aParams {
  float* x;
  const __half* xp[3];
  const int* bucket;
  const int* basea;
  const int* cnt;
  int off[3];
  const float* W[3];
  const float* bias[3];
  int nmaps;
};

__global__ __launch_bounds__(256) void k_p2a(P2aParams p) {
  __shared__ float Wl[3 * 4096];  // 48KB
  __shared__ float inl[32 * 64];
  __shared__ float bl[3 * 64];
  __shared__ int sb0[32], sbc[32];
  int t = threadIdx.x;
  int brow = blockIdx.x * 32;  // NA divisible by 32
  int nm = p.nmaps;
  for (int m = 0; m < nm; m++) {
#pragma unroll
    for (int i = 0; i < 4; i++)
      ((float4*)(Wl + m * 4096))[t + 256 * i] = ((const float4*)p.W[m])[t + 256 * i];
    if (t < 64) bl[m * 64 + t] = p.bias[m][t];
  }
  int c = t & 63, rq = t >> 6;
  float addv[8];
#pragma unroll
  for (int i = 0; i < 8; i++) addv[i] = 0.f;
  for (int m = 0; m < nm; m++) {
    __syncthreads();
    if (t < 32) {
      sb0[t] = p.basea[p.off[m] + brow + t];
      sbc[t] = p.cnt[p.off[m] + brow + t];
    }
    __syncthreads();
    const __half* src = p.xp[m];
#pragma unroll
    for (int i = 0; i < 8; i++) {
      int r = rq * 8 + i;
      int b0 = sb0[r], bc = sbc[r];
      float s = 0.f;
      for (int j = 0; j < bc; j++) {
        int e = p.bucket[b0 + j];
        s += __half2float(src[(long)e * 64 + c]);
      }
      inl[r * 64 + c] = s / (float)(bc > 0 ? bc : 1);
    }
    __syncthreads();
    float acc[8];
#pragma unroll
    for (int i = 0; i < 8; i++) acc[i] = 0.f;
    const float* Wm = Wl + m * 4096;
    for (int j = 0; j < 64; j += 4) {
      float w0 = Wm[(j + 0) * 64 + c], w1 = Wm[(j + 1) * 64 + c];
      float w2 = Wm[(j + 2) * 64 + c], w3 = Wm[(j + 3) * 64 + c];
#pragma unroll
      for (int i = 0; i < 8; i++) {
        int r = rq * 8 + i;
        float4 v = *(const float4*)&inl[r * 64 + j];
        acc[i] += v.x * w0 + v.y * w1 + v.z * w2 + v.w * w3;
      }
    }
    float bv = bl[m * 64 + c];
#pragma unroll
    for (int i = 0; i < 8; i++) {
      float v = acc[i] + bv;
      addv[i] += v > 0.f ? v : 0.f;
    }
  }
#pragma unroll
  for (int i = 0; i < 8; i++) {
    long a = brow + rq * 8 + i;
    p.x[a * 64 + c] += addv[i];
  }
}

// ---------------- batch mean: g1[b] = mean(x[a]) over CSR bucket ----------------

__global__ __launch_bounds__(256) void k_meanscatter(const float* src, const int* bucket,
                                                     const int* basea, const int* cnta,
                                                     float* dst, int nseg) {
  int wid = (blockIdx.x * 256 + threadIdx.x) >> 6;
  int lane = threadIdx.x & 63;
  if (wid >= nseg) return;
  int b0 = basea[wid], cnt = cnta[wid];
  float s = 0.f;
  for (int i = 0; i < cnt; i++) {
    int e = bucket[b0 + i];
    s += src[(long)e * 64 + lane];
  }
  dst[(long)wid * 64 + lane] = s / (float)(cnt > 0 ? cnt : 1);
}

// ---------------- head gemm: g2 = relu(g1 @ W + b) ----------------

__global__ __launch_bounds__(256) void k_head(const float* g1, const float* W,
                                              const float* bias, float* g2) {
  __shared__ float Wl[4096];
  __shared__ float inl[32 * 64];
  __shared__ float bl[64];
  int t = threadIdx.x;
  int brow = blockIdx.x * 32;
#pragma unroll
  for (int i = 0; i < 4; i++) ((float4*)Wl)[t + 256 * i] = ((const float4*)W)[t + 256 * i];
  if (t < 64) bl[t] = bias[t];
  __syncthreads();
#pragma unroll
  for (int i = 0; i < 2; i++) {
    int idx = t + 256 * i;
    int r = idx >> 4, q = idx & 15;
    ((float4*)inl)[idx] = ((const float4*)(g1 + (long)(brow + r) * 64))[q];
  }
  __syncthreads();
  int c = t & 63, rq = t >> 6;
  float acc[8];
#pragma unroll
  for (int i = 0; i < 8; i++) acc[i] = 0.f;
  for (int j = 0; j < 64; j += 4) {
    float w0 = Wl[(j + 0) * 64 + c], w1 = Wl[(j + 1) * 64 + c];
    float w2 = Wl[(j + 2) * 64 + c], w3 = Wl[(j + 3) * 64 + c];
#pragma unroll
    for (int i = 0; i < 8; i++) {
      int r = rq * 8 + i;
      float4 v = *(const float4*)&inl[r * 64 + j];
      acc[i] += v.x * w0 + v.y * w1 + v.z * w2 + v.w * w3;
    }
  }
#pragma unroll
  for (int i = 0; i < 8; i++) {
    long r = brow + rq * 8 + i;
    float v = acc[i] + bl[c];
    g2[r * 64 + c] = v > 0.f ? v : 0.f;
  }
}

__global__ __launch_bounds__(256) void k_final(const float* g2, const float* linW,
                                               const float* linb, float* out) {
  int wid = (blockIdx.x * 256 + threadIdx.x) >> 6;
  int lane = threadIdx.x & 63;
  if (wid >= NBATCH) return;
  float v = g2[(long)wid * 64 + lane] * linW[lane];
  for (int o = 32; o > 0; o >>= 1) v += __shfl_down(v, o, 64);
  if (lane == 0) out[wid] = v + linb[0];
}

__global__ __launch_bounds__(256) void k_zero_out(float* out, int n) {
  for (int i = blockIdx.x * 256 + threadIdx.x; i < n; i += gridDim.x * 256) out[i] = 0.f;
}

// ---------------- launcher ----------------

extern "C" void kernel_launch(void* const* d_in, const int* in_sizes, int n_in,
                              void* d_out, int out_size, void* d_ws, size_t ws_size,
                              hipStream_t stream) {
  (void)in_sizes; (void)n_in;

  const int* x_atom = (const int*)d_in[0];
  const int* vals[5] = {(const int*)d_in[1], (const int*)d_in[4], (const int*)d_in[7],
                        (const int*)d_in[10], (const int*)d_in[13]};
  const int* rowm[5] = {(const int*)d_in[2], (const int*)d_in[5], (const int*)d_in[8],
                        (const int*)d_in[11], (const int*)d_in[14]};
  const int* batch = (const int*)d_in[16];
  const float* aemb0 = (const float*)d_in[17];
  const float* aemb1 = (const float*)d_in[18];
  const float* aemb2 = (const float*)d_in[19];
  const float* path_emb = (const float*)d_in[20];
  const float* cycle_emb = (const float*)d_in[21];
  const float* pW_a2p = (const float*)d_in[22];
  const float* pb_a2p = (const float*)d_in[23];
  const float* pW_p2a = (const float*)d_in[24];
  const float* pb_p2a = (const float*)d_in[25];
  const float* pK = (const float*)d_in[26];
  const float* pKb = (const float*)d_in[27];
  const float* cW_a2p = (const float*)d_in[28];
  const float* cb_a2p = (const float*)d_in[29];
  const float* cW_p2a = (const float*)d_in[30];
  const float* cb_p2a = (const float*)d_in[31];
  const float* cK = (const float*)d_in[32];
  const float* cKb = (const float*)d_in[33];
  const float* alW = (const float*)d_in[34];
  const float* alb = (const float*)d_in[35];
  const float* linW = (const float*)d_in[36];
  const float* linb = (const float*)d_in[37];

  static const int Em[5] = {300000, 400000, 500000, 200000, 240000};
  static const int Km[5] = {3, 4, 5, 5, 6};
  static const int Ppb[5] = {32, 24, 16, 16, 16};  // paths/block -> R in {96,96,80,80,96}
  const int CNT_N = 5 * 100000 + NBATCH;  // 504096
  const int BUCKET_N = 1640000 + 100000;  // 1740000

  char* ws = (char*)d_ws;
  size_t off = 0;
  auto alloc = [&](size_t nbytes) -> char* {
    char* p = ws + off;
    off = (off + nbytes + 255) & ~(size_t)255;
    return p;
  };
  float* x = (float*)alloc((size_t)NA * 64 * 4);
  __half* xp[5];
  for (int m = 0; m < 5; m++) xp[m] = (__half*)alloc((size_t)Em[m] * 64 * 2);
  float* g1 = (float*)alloc((size_t)NBATCH * 64 * 4);
  float* g2 = (float*)alloc((size_t)NBATCH * 64 * 4);
  int* cnt = (int*)alloc((size_t)CNT_N * 4);
  int* basea = (int*)alloc((size_t)CNT_N * 4);
  int* cursor = (int*)alloc((size_t)CNT_N * 4);
  int* bucket = (int*)alloc((size_t)BUCKET_N * 4);
  int* bsums = (int*)alloc(256 * 4);
  f16* Bp = (f16*)alloc((size_t)10 * 12288 * 2);  // prepacked conv kernels

  if (ws_size < off) {  // workspace too small: emit readable failure, not a fault
    k_zero_out<<<16, 256, 0, stream>>>((float*)d_out, out_size);
    return;
  }

  // ---- CSR build
  MapsParams mp;
  {
    int s = 0;
    for (int m = 0; m < 5; m++) {
      mp.row[m] = rowm[m]; mp.cnt_off[m] = m * 100000;
      mp.start[m] = s; s += Em[m];
    }
    mp.row[5] = batch; mp.cnt_off[5] = 500000; mp.start[5] = s;
    mp.total = s + NA;
  }
  hipMemsetAsync(cnt, 0, (size_t)CNT_N * 4, stream);
  k_count<<<2048, 256, 0, stream>>>(mp, cnt);
  int nbScan = (CNT_N + 2047) / 2048;  // 247
  k_scanA<<<nbScan, 256, 0, stream>>>(cnt, basea, bsums, CNT_N);
  k_scanB<<<1, 256, 0, stream>>>(bsums, nbScan);
  k_scanC<<<nbScan, 256, 0, stream>>>(basea, bsums, CNT_N);
  hipMemcpyAsync(cursor, basea, (size_t)CNT_N * 4, hipMemcpyDeviceToDevice, stream);
  k_fill<<<2048, 256, 0, stream>>>(mp, cursor, bucket);

  // ---- prepack conv weights + feature init
  k_prepB<<<480, 256, 0, stream>>>(pK, cK, Bp);
  k_atom_init<<<NA * 16 / 256, 256, 0, stream>>>(x_atom, aemb0, aemb1, aemb2, x);
  {
    PInit pp;
    int s8 = 0;
    for (int m = 0; m < 5; m++) {
      pp.dst[m] = xp[m];
      pp.vals[m] = vals[m];
      pp.tab[m] = (m < 3) ? (path_emb + m * 6 * 64) : (cycle_emb + (m - 3) * 4 * 64);
      pp.start8[m] = s8;
      s8 += Em[m] * 8;
    }
    pp.total8 = s8;
    k_path_init<<<8192, 256, 0, stream>>>(pp);
  }

  // ---- layers
  for (int l = 0; l < 2; l++) {
    // === paths group (maps 0..2), non-cyclic
    {
      A2pParams gp{};
      gp.nseg = 3; gp.x = x;
      int bs = 0;
      for (int m = 0; m < 3; m++) {
        gp.gidx[m] = rowm[m]; gp.out[m] = xp[m];
        gp.W[m] = pW_a2p + (l * 3 + m) * 4096;
        gp.bias[m] = pb_a2p + (l * 3 + m) * 64;
        gp.blk_start[m] = bs;
        bs += Em[m] / 32;
      }
      k_a2p<<<bs, 256, 0, stream>>>(gp);

      ConvParams cp{};
      cp.nseg = 3; cp.cyclic = 0;
      int cbs = 0;
      for (int m = 0; m < 3; m++) {
        cp.buf[m] = (f16*)xp[m];
        cp.Bp[m] = Bp + (size_t)(l * 3 + m) * 12288;
        cp.Kb[m] = pKb + (l * 3 + m) * 64;
        cp.k[m] = Km[m]; cp.P[m] = Em[m] / Km[m]; cp.ppb[m] = Ppb[m];
        cp.blk_start[m] = cbs;
        cbs += (cp.P[m] + cp.ppb[m] - 1) / cp.ppb[m];
      }
      k_conv<<<cbs, 256, 0, stream>>>(cp);

      P2aParams bp{};
      bp.x = x; bp.bucket = bucket; bp.basea = basea; bp.cnt = cnt; bp.nmaps = 3;
      for (int m = 0; m < 3; m++) {
        bp.xp[m] = xp[m]; bp.off[m] = m * 100000;
        bp.W[m] = pW_p2a + (l * 3 + m) * 4096;
        bp.bias[m] = pb_p2a + (l * 3 + m) * 64;
      }
      k_p2a<<<NA / 32, 256, 0, stream>>>(bp);
    }
    // === cycles group (maps 3..4), cyclic
    {
      A2pParams gp{};
      gp.nseg = 2; gp.x = x;
      int bs = 0;
      for (int m = 3; m < 5; m++) {
        int i = m - 3;
        gp.gidx[i] = rowm[m]; gp.out[i] = xp[m];
        gp.W[i] = cW_a2p + (l * 2 + i) * 4096;
        gp.bias[i] = cb_a2p + (l * 2 + i) * 64;
        gp.blk_start[i] = bs;
        bs += Em[m] / 32;
      }
      k_a2p<<<bs, 256, 0, stream>>>(gp);

      ConvParams cp{};
      cp.nseg = 2; cp.cyclic = 1;
      int cbs = 0;
      for (int m = 3; m < 5; m++) {
        int i = m - 3;
        cp.buf[i] = (f16*)xp[m];
        cp.Bp[i] = Bp + (size_t)(6 + l * 2 + i) * 12288;
        cp.Kb[i] = cKb + (l * 2 + i) * 64;
        cp.k[i] = Km[m]; cp.P[i] = Em[m] / Km[m]; cp.ppb[i] = Ppb[m];
        cp.blk_start[i] = cbs;
        cbs += (cp.P[i] + cp.ppb[i] - 1) / cp.ppb[i];
      }
      k_conv<<<cbs, 256, 0, stream>>>(cp);

      P2aParams bp{};
      bp.x = x; bp.bucket = bucket; bp.basea = basea; bp.cnt = cnt; bp.nmaps = 2;
      for (int m = 3; m < 5; m++) {
        int i = m - 3;
        bp.xp[i] = xp[m]; bp.off[i] = m * 100000;
        bp.W[i] = cW_p2a + (l * 2 + i) * 4096;
        bp.bias[i] = cb_p2a + (l * 2 + i) * 64;
      }
      k_p2a<<<NA / 32, 256, 0, stream>>>(bp);
    }
  }

  // ---- head
  k_meanscatter<<<NBATCH / 4, 256, 0, stream>>>(x, bucket, basea + 500000, cnt + 500000,
                                                g1, NBATCH);
  k_head<<<NBATCH / 32, 256, 0, stream>>>(g1, alW, alb, g2);
  k_final<<<NBATCH / 4, 256, 0, stream>>>(g2, linW, linb, (float*)d_out);
}